// Round 1
// baseline (809.337 us; speedup 1.0000x reference)
//
#include <hip/hip_runtime.h>

// EMACodebook update: segment-mean of L2-normalized rows + conditional EMA.
// BN=524288, D=256, K=1024. Strategy: counting-sort patch indices by label,
// then one block per class reduces its member rows without any data atomics.

constexpr int K = 1024;
constexpr int D = 256;
constexpr float MOMENTUM = 0.9f;
constexpr float EPS_NORM = 1e-12f;
constexpr float EPS_CNT = 1e-6f;

__global__ void zero_k(int* __restrict__ hist) {
    hist[threadIdx.x] = 0;
}

__global__ void hist_k(const int* __restrict__ labels, int bn, int* __restrict__ hist) {
    __shared__ int lh[K];
    for (int i = threadIdx.x; i < K; i += blockDim.x) lh[i] = 0;
    __syncthreads();
    for (int i = blockIdx.x * blockDim.x + threadIdx.x; i < bn; i += gridDim.x * blockDim.x)
        atomicAdd(&lh[labels[i]], 1);
    __syncthreads();
    for (int i = threadIdx.x; i < K; i += blockDim.x) {
        int v = lh[i];
        if (v) atomicAdd(&hist[i], v);
    }
}

// One block of K threads: exclusive prefix sum (Hillis-Steele in LDS).
__global__ void prefix_k(const int* __restrict__ hist, int* __restrict__ base,
                         int* __restrict__ cursor) {
    __shared__ int tmp[K];
    int t = threadIdx.x;
    tmp[t] = hist[t];
    __syncthreads();
    for (int off = 1; off < K; off <<= 1) {
        int add = (t >= off) ? tmp[t - off] : 0;
        __syncthreads();
        tmp[t] += add;
        __syncthreads();
    }
    int excl = (t == 0) ? 0 : tmp[t - 1];
    base[t] = excl;
    cursor[t] = excl;
}

__global__ void scatter_k(const int* __restrict__ labels, int bn,
                          int* __restrict__ cursor, int* __restrict__ sorted) {
    for (int i = blockIdx.x * blockDim.x + threadIdx.x; i < bn; i += gridDim.x * blockDim.x) {
        int l = labels[i];
        int pos = atomicAdd(&cursor[l], 1);
        sorted[pos] = i;
    }
}

// One block per class. 4 waves; wave w reduces patches w, w+4, ...
// Each lane holds 4 columns (lane*4 .. lane*4+3) via float4 loads (1KB/row, coalesced).
__global__ __launch_bounds__(256) void finalize_k(
        const float* __restrict__ proj, const int* __restrict__ sorted,
        const int* __restrict__ base, const int* __restrict__ hist,
        const float* __restrict__ codebook, const int* __restrict__ pcounts,
        float* __restrict__ out_cb, float* __restrict__ out_cnt) {
    const int k = blockIdx.x;
    const int t = threadIdx.x;
    const int wave = t >> 6;
    const int lane = t & 63;
    const int cnt = hist[k];
    const int b0 = base[k];

    float a0 = 0.f, a1 = 0.f, a2 = 0.f, a3 = 0.f;

    if (cnt > 0) {  // uniform across block
        int p = wave;
        // 2-deep index pipeline so idx-load latency doesn't serialize with row loads
        int idx0 = sorted[b0 + min(p, cnt - 1)];
        int idx1 = sorted[b0 + min(p + 4, cnt - 1)];
        float4 v0 = make_float4(0.f, 0.f, 0.f, 0.f);
        if (p < cnt)
            v0 = *reinterpret_cast<const float4*>(proj + (size_t)idx0 * D + lane * 4);
        for (; p < cnt; p += 4) {
            int idx2 = sorted[b0 + min(p + 8, cnt - 1)];
            float4 v1 = *reinterpret_cast<const float4*>(proj + (size_t)idx1 * D + lane * 4);
            // row L2 norm across the wave
            float ss = v0.x * v0.x + v0.y * v0.y + v0.z * v0.z + v0.w * v0.w;
            #pragma unroll
            for (int o = 32; o >= 1; o >>= 1) ss += __shfl_xor(ss, o, 64);
            float inv = 1.0f / fmaxf(sqrtf(ss), EPS_NORM);
            a0 += v0.x * inv; a1 += v0.y * inv; a2 += v0.z * inv; a3 += v0.w * inv;
            v0 = v1;
            idx1 = idx2;
        }
    }

    __shared__ float s_acc[4][D];
    s_acc[wave][lane * 4 + 0] = a0;
    s_acc[wave][lane * 4 + 1] = a1;
    s_acc[wave][lane * 4 + 2] = a2;
    s_acc[wave][lane * 4 + 3] = a3;
    __syncthreads();

    float sum = s_acc[0][t] + s_acc[1][t] + s_acc[2][t] + s_acc[3][t];
    float cb = codebook[(size_t)k * D + t];
    float outv = cb;

    __shared__ float red[D];
    if (cnt > 0) {  // uniform: syncthreads inside is safe
        float mean = sum / fmaxf((float)cnt, EPS_CNT);
        red[t] = mean * mean;
        __syncthreads();
        for (int s = 128; s > 0; s >>= 1) {
            if (t < s) red[t] += red[t + s];
            __syncthreads();
        }
        float n1 = fmaxf(sqrtf(red[0]), EPS_NORM);
        __syncthreads();
        float proto = mean / n1;
        float ep = MOMENTUM * cb + (1.0f - MOMENTUM) * proto;
        red[t] = ep * ep;
        __syncthreads();
        for (int s = 128; s > 0; s >>= 1) {
            if (t < s) red[t] += red[t + s];
            __syncthreads();
        }
        float n2 = fmaxf(sqrtf(red[0]), EPS_NORM);
        float ema = ep / n2;
        outv = (pcounts[k] == 0) ? proto : ema;
    }

    out_cb[(size_t)k * D + t] = outv;
    if (t == 0) out_cnt[k] = (float)(pcounts[k] + (cnt > 0 ? 1 : 0));
}

extern "C" void kernel_launch(void* const* d_in, const int* in_sizes, int n_in,
                              void* d_out, int out_size, void* d_ws, size_t ws_size,
                              hipStream_t stream) {
    const float* proj     = (const float*)d_in[0];
    const int*   labels   = (const int*)d_in[1];
    const float* codebook = (const float*)d_in[2];
    const int*   pcounts  = (const int*)d_in[3];
    const int BN = in_sizes[0] / D;

    float* out_cb  = (float*)d_out;
    float* out_cnt = out_cb + (size_t)K * D;

    int* hist   = (int*)d_ws;     // K
    int* base   = hist + K;       // K
    int* cursor = base + K;       // K
    int* sorted = cursor + K;     // BN

    zero_k<<<1, K, 0, stream>>>(hist);
    hist_k<<<256, 256, 0, stream>>>(labels, BN, hist);
    prefix_k<<<1, K, 0, stream>>>(hist, base, cursor);
    scatter_k<<<256, 256, 0, stream>>>(labels, BN, cursor, sorted);
    finalize_k<<<K, 256, 0, stream>>>(proj, sorted, base, hist, codebook, pcounts,
                                      out_cb, out_cnt);
}